// Round 9
// baseline (1463.710 us; speedup 1.0000x reference)
//
#include <hip/hip_runtime.h>
#include <hip/hip_bf16.h>
#include <stdint.h>

// ---------------------------------------------------------------------------
// EncodeProcessDecode (MeshGraphNets) on MI355X — Round 9:
//  r8 structure (direct A-frags, B-fragment-ordered W) with 32-k W chunks:
//  2x8KB LDS double buffer, 1 barrier/chunk, LDS 33 KB -> 4 blocks/CU,
//  A-frag prefetch depth 2. Numerics bit-identical (absmax 0.0703125).
//
#define N_NODES 10000
#define N_EDGES 80000
#define L 128
#define STEPS 15
#define LN_EPS 1e-5f
#define NTHR 256
#define H_STRIDE 272

typedef short short8 __attribute__((ext_vector_type(8)));
typedef float floatx4 __attribute__((ext_vector_type(4)));

__device__ __forceinline__ float bf2f(const __hip_bfloat16 x) {
    return __bfloat162float(x);
}
__device__ __forceinline__ float ldmix(const void* p, int idx, int isf32) {
    return isf32 ? ((const float*)p)[idx]
                 : bf2f(((const __hip_bfloat16*)p)[idx]);
}

// ---------------------------------------------------------------------------
__global__ void detect_dtype(const uint32_t* __restrict__ nf, int* cnt) {
    int c = 0;
    for (int i = blockIdx.x * blockDim.x + threadIdx.x; i < 60000;
         i += gridDim.x * blockDim.x) {
        const uint32_t w = nf[i];
        c += (((w >> 7) & 0xFF) >= 0xC6) + (((w >> 23) & 0xFF) >= 0xC6);
    }
    atomicAdd(cnt, c);
}

// ---------------------------------------------------------------------------
// Weights -> bf16 in B-fragment order:
// per 32-k chunk c2: [ct(8)][lane(64)][j(8)] where
//   k = c2*32 + (lane>>4)*8 + j, col = ct*16 + (lane&15)
#define N_TMATS 14
struct TAll {
    const void* src[N_TMATS];
    long long cum[N_TMATS + 1];
    int K[N_TMATS], N[N_TMATS], Kpad[N_TMATS];
};

__global__ void transpose_all(TAll a, const int* __restrict__ cnt,
                              __hip_bfloat16* __restrict__ pool) {
    const int isf32 = (*cnt > 1000);
    const long long total = a.cum[N_TMATS];
    for (long long i = blockIdx.x * (long long)blockDim.x + threadIdx.x;
         i < total; i += gridDim.x * (long long)blockDim.x) {
        int e = 0;
        #pragma unroll 1
        for (int j = 1; j < N_TMATS; j++) if (i >= a.cum[j]) e = j;
        const long long r = i - a.cum[e];
        const int per = a.N[e] * a.Kpad[e];
        const int m = (int)(r / per);
        int r2 = (int)(r - (long long)m * per);
        const int c2   = r2 >> 12;           // /4096
        const int rem  = r2 & 4095;
        const int ct   = rem >> 9;
        const int lane = (rem >> 3) & 63;
        const int j    = rem & 7;
        const int k    = c2 * 32 + (lane >> 4) * 8 + j;
        const int col  = ct * 16 + (lane & 15);
        float v = 0.f;
        if (k < a.K[e]) v = ldmix(a.src[e], (m * a.K[e] + k) * a.N[e] + col, isf32);
        pool[i] = __float2bfloat16(v);
    }
}

// fN plain; fE permuted to sorted-edge order via elist
__global__ void convert_feats(const void* __restrict__ nf,
                              const void* __restrict__ ef,
                              const int* __restrict__ cnt,
                              const int* __restrict__ elist,
                              __hip_bfloat16* __restrict__ fN,
                              __hip_bfloat16* __restrict__ fE)
{
    const int isf32 = (*cnt > 1000);
    const int totN = N_NODES * 32;
    const int totE = N_EDGES * 32;
    for (int i = blockIdx.x * blockDim.x + threadIdx.x; i < totN + totE;
         i += gridDim.x * blockDim.x) {
        if (i < totN) {
            const int r = i >> 5, c = i & 31;
            fN[i] = __float2bfloat16(c < 12 ? ldmix(nf, r * 12 + c, isf32) : 0.f);
        } else {
            const int j = i - totN;
            const int r = j >> 5, c = j & 31;
            const int e = elist[r];
            fE[j] = __float2bfloat16(c < 7 ? ldmix(ef, e * 7 + c, isf32) : 0.f);
        }
    }
}

// ---------------------------------------------------------------------------
// CSR build (receiver lists)
__global__ void csr_hist(const int* __restrict__ rcv, int* __restrict__ deg) {
    for (int i = blockIdx.x * blockDim.x + threadIdx.x; i < N_EDGES;
         i += gridDim.x * blockDim.x)
        atomicAdd(&deg[rcv[i]], 1);
}

__global__ void csr_scan(const int* __restrict__ deg, int* __restrict__ rowptr,
                         int* __restrict__ cursor) {
    __shared__ int part[256];
    __shared__ int partx[257];
    const int t = threadIdx.x;
    int s = 0;
    for (int j = 0; j < 40; j++) {
        const int i = t * 40 + j;
        if (i < N_NODES) s += deg[i];
    }
    part[t] = s;
    __syncthreads();
    if (t == 0) {
        int r = 0;
        for (int k = 0; k < 256; k++) { partx[k] = r; r += part[k]; }
        partx[256] = r;
    }
    __syncthreads();
    int run = partx[t];
    for (int j = 0; j < 40; j++) {
        const int i = t * 40 + j;
        if (i < N_NODES) {
            rowptr[i] = run;
            cursor[i] = run;
            run += deg[i];
        }
    }
    if (t == 255) rowptr[N_NODES] = partx[256];
}

__global__ void csr_scatter(const int* __restrict__ rcv, int* __restrict__ cursor,
                            int* __restrict__ elist) {
    for (int i = blockIdx.x * blockDim.x + threadIdx.x; i < N_EDGES;
         i += gridDim.x * blockDim.x) {
        const int p = atomicAdd(&cursor[rcv[i]], 1);
        elist[p] = i;
    }
}

__global__ void sort_meta(const int* __restrict__ snd, const int* __restrict__ rcv,
                          const int* __restrict__ elist,
                          int* __restrict__ ssnd, int* __restrict__ srcv) {
    for (int i = blockIdx.x * blockDim.x + threadIdx.x; i < N_EDGES;
         i += gridDim.x * blockDim.x) {
        const int e = elist[i];
        ssnd[i] = snd[e];
        srcv[i] = rcv[e];
    }
}

// agg16[v] = bf16( sum over contiguous sorted rows [rowptr[v],rowptr[v+1]) )
__global__ __launch_bounds__(256)
void csr_agg(const int* __restrict__ rowptr,
             const __hip_bfloat16* __restrict__ ln16,
             __hip_bfloat16* __restrict__ agg16)
{
    const int g = threadIdx.x >> 5;
    const int lane = threadIdx.x & 31;
    const int v = blockIdx.x * 8 + g;
    if (v >= N_NODES) return;
    const int c0 = lane * 4;
    float s0 = 0.f, s1 = 0.f, s2 = 0.f, s3 = 0.f;
    int j = rowptr[v];
    const int en = rowptr[v + 1];
    for (; j + 1 < en; j += 2) {
        union { uint2 w; __hip_bfloat16 h[4]; } u0, u1;
        u0.w = *(const uint2*)(ln16 + (size_t)j * L + c0);
        u1.w = *(const uint2*)(ln16 + (size_t)(j + 1) * L + c0);
        s0 += bf2f(u0.h[0]); s1 += bf2f(u0.h[1]); s2 += bf2f(u0.h[2]); s3 += bf2f(u0.h[3]);
        s0 += bf2f(u1.h[0]); s1 += bf2f(u1.h[1]); s2 += bf2f(u1.h[2]); s3 += bf2f(u1.h[3]);
    }
    for (; j < en; j++) {
        union { uint2 w; __hip_bfloat16 h[4]; } u;
        u.w = *(const uint2*)(ln16 + (size_t)j * L + c0);
        s0 += bf2f(u.h[0]); s1 += bf2f(u.h[1]); s2 += bf2f(u.h[2]); s3 += bf2f(u.h[3]);
    }
    union { uint2 w; __hip_bfloat16 h[4]; } o;
    o.h[0] = __float2bfloat16(s0); o.h[1] = __float2bfloat16(s1);
    o.h[2] = __float2bfloat16(s2); o.h[3] = __float2bfloat16(s3);
    *(uint2*)(agg16 + (size_t)v * L + c0) = o.w;
}

// ---------------------------------------------------------------------------
enum AMode { A_PLAIN = 0, A_FEAT = 1, A_CAT = 2 };
enum Epi   { E_LN_STORE = 0, E_LN_EDGE = 1, E_LN_NODE = 2, E_DEC = 3 };

// Fused NL-layer MLP. Block: 64 rows x 128 cols, 4 waves; wave w owns rows
// [w*16, w*16+16). A-frags direct global->reg (prefetch depth 2); W in
// B-fragment order, 2x8KB LDS double buffer, 1 barrier per 32-k chunk.
template <int AMODE, int EPI, int NL, int K0>
__global__ __launch_bounds__(NTHR, 4)
void fused_mlp(const __hip_bfloat16* __restrict__ A, int lda, int M,
               const __hip_bfloat16* __restrict__ WT0,
               const __hip_bfloat16* __restrict__ WT1,
               const __hip_bfloat16* __restrict__ WT2,
               const void* __restrict__ b0,
               const void* __restrict__ b1,
               const void* __restrict__ b2,
               const void* __restrict__ g,
               const void* __restrict__ beta,
               int poff,
               const int* __restrict__ cnt,
               const __hip_bfloat16* __restrict__ n16,
               const __hip_bfloat16* __restrict__ e16s,
               const __hip_bfloat16* __restrict__ agg16,
               const int* __restrict__ ssnd,
               const int* __restrict__ srcv,
               float* res32,
               __hip_bfloat16* res16,
               __hip_bfloat16* __restrict__ lnout,
               const void* __restrict__ dW,
               const void* __restrict__ db,
               void* __restrict__ dout)
{
    __shared__ __align__(16) char lds[17408 + 16384];
    char* wbuf = lds + 17408;

    const int tid  = threadIdx.x;
    const int wv   = tid >> 6;
    const int lane = tid & 63;
    const int quad = lane >> 4;
    const int m15  = lane & 15;
    const int row0 = blockIdx.x * 64;
    const int isf32 = (*cnt > 1000);

    char* hw = lds + wv * 4352;    // this wave's 16x128 activation buffer

    const int rw = row0 + wv * 16 + m15;      // this lane's output row
    const int rc = rw < M ? rw : M - 1;       // clamped for loads

    int sI = 0, rI = 0;
    if constexpr (AMODE == A_FEAT) { sI = ssnd[rc]; rI = srcv[rc]; }

    auto aFrag = [&](int kchunk) -> short8 {
        const int k0 = kchunk * 32 + quad * 8;
        const __hip_bfloat16* sp;
        if constexpr (AMODE == A_PLAIN) {
            sp = A + (size_t)rc * lda + k0;
        } else if constexpr (AMODE == A_FEAT) {
            if (k0 < L)          sp = n16  + (size_t)sI * L + k0;
            else if (k0 < 2 * L) sp = n16  + (size_t)rI * L + (k0 - L);
            else                 sp = e16s + (size_t)rc * L + (k0 - 2 * L);
        } else {
            if (k0 < L) sp = n16   + (size_t)rc * L + k0;
            else        sp = agg16 + (size_t)rc * L + (k0 - L);
        }
        return *(const short8*)sp;
    };
    auto loadWc = [&](const __hip_bfloat16* base, int c, int4& x, int4& y) {
        const __hip_bfloat16* p = base + (size_t)c * 4096 + tid * 16;
        x = *(const int4*)p;
        y = *(const int4*)(p + 8);
    };
    auto storeWc = [&](int b, const int4& x, const int4& y) {
        *(int4*)(wbuf + b * 8192 + tid * 32)      = x;
        *(int4*)(wbuf + b * 8192 + tid * 32 + 16) = y;
    };
    auto breadc = [&](int b, int ct) -> short8 {
        return *(const short8*)(wbuf + b * 8192 + ct * 1024 + lane * 16);
    };

    constexpr int C0 = K0 / 32;

    int4 w0, w1;
    short8 aCur, aNext;
    int buf = 0;
    floatx4 acc[8];

    // ===================== layer 0 =====================
    #pragma unroll
    for (int ct = 0; ct < 8; ct++) acc[ct] = (floatx4)0.f;

    loadWc(WT0, 0, w0, w1);
    aCur = aFrag(0);
    if constexpr (C0 > 1) aNext = aFrag(1);

    for (int c = 0; c < C0; c++) {
        storeWc(buf, w0, w1);
        __syncthreads();
        const short8 a = aCur;
        aCur = aNext;
        if (c + 2 < C0) aNext = aFrag(c + 2);
        if (c + 1 < C0) loadWc(WT0, c + 1, w0, w1);
        else            loadWc(WT1, 0, w0, w1);    // chain into layer 1
        #pragma unroll
        for (int ct = 0; ct < 8; ct++)
            acc[ct] = __builtin_amdgcn_mfma_f32_16x16x32_bf16(a, breadc(buf, ct), acc[ct], 0, 0, 0);
        buf ^= 1;
    }
    {
        float bb[8];
        #pragma unroll
        for (int ct = 0; ct < 8; ct++) bb[ct] = ldmix(b0, poff + ct * 16 + m15, isf32);
        #pragma unroll
        for (int ct = 0; ct < 8; ct++)
            #pragma unroll
            for (int i = 0; i < 4; i++) {
                const int rl = quad * 4 + i;
                const int col = ct * 16 + m15;
                *(__hip_bfloat16*)(hw + rl * H_STRIDE + col * 2) =
                    __float2bfloat16(fmaxf(acc[ct][i] + bb[ct], 0.f));
            }
    }

    // ===================== layer 1 =====================
    {
        #pragma unroll
        for (int ct = 0; ct < 8; ct++) acc[ct] = (floatx4)0.f;
        short8 af[4];
        #pragma unroll
        for (int c = 0; c < 4; c++)
            af[c] = *(const short8*)(hw + m15 * H_STRIDE + c * 64 + quad * 16);
        for (int c = 0; c < 4; c++) {
            storeWc(buf, w0, w1);
            __syncthreads();
            if (c < 3)               loadWc(WT1, c + 1, w0, w1);
            else if constexpr (NL == 3) loadWc(WT2, 0, w0, w1);
            #pragma unroll
            for (int ct = 0; ct < 8; ct++)
                acc[ct] = __builtin_amdgcn_mfma_f32_16x16x32_bf16(af[c], breadc(buf, ct), acc[ct], 0, 0, 0);
            buf ^= 1;
        }
        float bb[8];
        #pragma unroll
        for (int ct = 0; ct < 8; ct++) bb[ct] = ldmix(b1, poff + ct * 16 + m15, isf32);
        #pragma unroll
        for (int ct = 0; ct < 8; ct++)
            #pragma unroll
            for (int i = 0; i < 4; i++) {
                const int rl = quad * 4 + i;
                const int col = ct * 16 + m15;
                *(__hip_bfloat16*)(hw + rl * H_STRIDE + col * 2) =
                    __float2bfloat16(fmaxf(acc[ct][i] + bb[ct], 0.f));
            }
    }

    if constexpr (NL == 3) {
        // ===================== layer 2 + LN epilogue =====================
        #pragma unroll
        for (int ct = 0; ct < 8; ct++) acc[ct] = (floatx4)0.f;
        short8 af[4];
        #pragma unroll
        for (int c = 0; c < 4; c++)
            af[c] = *(const short8*)(hw + m15 * H_STRIDE + c * 64 + quad * 16);
        for (int c = 0; c < 4; c++) {
            storeWc(buf, w0, w1);
            __syncthreads();
            if (c < 3) loadWc(WT2, c + 1, w0, w1);
            #pragma unroll
            for (int ct = 0; ct < 8; ct++)
                acc[ct] = __builtin_amdgcn_mfma_f32_16x16x32_bf16(af[c], breadc(buf, ct), acc[ct], 0, 0, 0);
            buf ^= 1;
        }
        float bb[8], gg[8], be[8];
        #pragma unroll
        for (int ct = 0; ct < 8; ct++) {
            bb[ct] = ldmix(b2,   poff + ct * 16 + m15, isf32);
            gg[ct] = ldmix(g,    poff + ct * 16 + m15, isf32);
            be[ct] = ldmix(beta, poff + ct * 16 + m15, isf32);
        }
        #pragma unroll
        for (int i = 0; i < 4; i++) {
            float t[8], s = 0.f, s2 = 0.f;
            #pragma unroll
            for (int ct = 0; ct < 8; ct++) {
                t[ct] = acc[ct][i] + bb[ct];
                s  += t[ct];
                s2 += t[ct] * t[ct];
            }
            #pragma unroll
            for (int m = 1; m < 16; m <<= 1) {
                s  += __shfl_xor(s,  m, 64);
                s2 += __shfl_xor(s2, m, 64);
            }
            const float mean = s * (1.f / 128.f);
            const float var  = s2 * (1.f / 128.f) - mean * mean;
            const float inv  = rsqrtf(fmaxf(var, 0.f) + LN_EPS);
            const int rg = row0 + wv * 16 + quad * 4 + i;
            if (rg < M) {
                #pragma unroll
                for (int ct = 0; ct < 8; ct++) {
                    const int col = ct * 16 + m15;
                    const float o = (t[ct] - mean) * inv * gg[ct] + be[ct];
                    const size_t idx = (size_t)rg * L + col;
                    if constexpr (EPI == E_LN_STORE) {
                        res32[idx] = o;
                        if (res16) res16[idx] = __float2bfloat16(o);
                    } else if constexpr (EPI == E_LN_NODE) {
                        const float nw = res32[idx] + o;
                        res32[idx] = nw;
                        res16[idx] = __float2bfloat16(nw);
                    } else { // E_LN_EDGE
                        const float nw = res32[idx] + o;
                        res32[idx] = nw;
                        res16[idx] = __float2bfloat16(nw);
                        lnout[idx] = __float2bfloat16(o);
                    }
                }
            }
        }
    } else {
        // ===================== decoder head =====================
        __syncthreads();
        float* Wl = (float*)wbuf;
        for (int i = tid; i < 3 * L; i += NTHR) {
            const int o = i / L, k = i - o * L;
            Wl[o * L + k] = ldmix(dW, k * 3 + o, isf32);
        }
        __syncthreads();
        if (tid < 64) {
            const int rg = row0 + tid;
            if (rg < M) {
                const __hip_bfloat16* hr =
                    (const __hip_bfloat16*)(lds + (tid >> 4) * 4352 + (tid & 15) * H_STRIDE);
                float s0 = ldmix(db, 0, isf32);
                float s1 = ldmix(db, 1, isf32);
                float s2 = ldmix(db, 2, isf32);
                #pragma unroll 8
                for (int k = 0; k < L; k++) {
                    const float hv = bf2f(hr[k]);
                    s0 += hv * Wl[k];
                    s1 += hv * Wl[L + k];
                    s2 += hv * Wl[2 * L + k];
                }
                if (isf32) {
                    float* o = (float*)dout;
                    o[rg * 3 + 0] = s0; o[rg * 3 + 1] = s1; o[rg * 3 + 2] = s2;
                } else {
                    __hip_bfloat16* o = (__hip_bfloat16*)dout;
                    o[rg * 3 + 0] = __float2bfloat16(s0);
                    o[rg * 3 + 1] = __float2bfloat16(s1);
                    o[rg * 3 + 2] = __float2bfloat16(s2);
                }
            }
        }
    }
}

// ---------------------------------------------------------------------------
extern "C" void kernel_launch(void* const* d_in, const int* in_sizes, int n_in,
                              void* d_out, int out_size, void* d_ws, size_t ws_size,
                              hipStream_t stream)
{
    (void)in_sizes; (void)n_in; (void)out_size; (void)ws_size;
    const int* snd = (const int*)d_in[2];
    const int* rcv = (const int*)d_in[3];

    char* ws = (char*)d_ws;
    int* cnt = (int*)ws;                              ws += 256;
    auto takeB = [&](size_t el) {
        __hip_bfloat16* p = (__hip_bfloat16*)ws;
        ws += ((el * 2 + 255) & ~255ull);
        return p;
    };
    auto takeF = [&](size_t el) {
        float* p = (float*)ws;
        ws += ((el * 4 + 255) & ~255ull);
        return p;
    };
    auto takeI = [&](size_t el) {
        int* p = (int*)ws;
        ws += ((el * 4 + 255) & ~255ull);
        return p;
    };

    const int srcIdx[N_TMATS] = {4, 6, 8, 12, 14, 16, 20, 22, 24, 28, 30, 32, 36, 38};
    const int tK[N_TMATS]    = {12, 128, 128, 7, 128, 128, 384, 128, 128, 256, 128, 128, 128, 128};
    const int tKp[N_TMATS]   = {32, 128, 128, 32, 128, 128, 384, 128, 128, 256, 128, 128, 128, 128};
    const int tNm[N_TMATS]   = {1, 1, 1, 1, 1, 1, STEPS, STEPS, STEPS, STEPS, STEPS, STEPS, 1, 1};
    TAll ta;
    long long cum = 0;
    __hip_bfloat16* wmat[N_TMATS];
    __hip_bfloat16* wpool = (__hip_bfloat16*)ws;
    for (int j = 0; j < N_TMATS; j++) {
        ta.src[j] = d_in[srcIdx[j]];
        ta.cum[j] = cum;
        ta.K[j] = tK[j]; ta.N[j] = 128; ta.Kpad[j] = tKp[j];
        wmat[j] = wpool + cum;
        cum += (long long)tNm[j] * 128 * tKp[j];
    }
    ta.cum[N_TMATS] = cum;
    ws += ((cum * 2 + 255) & ~255ull);

    float* n32 = takeF((size_t)N_NODES * L);
    float* e32 = takeF((size_t)N_EDGES * L);
    __hip_bfloat16* n16   = takeB((size_t)N_NODES * L);
    __hip_bfloat16* e16   = takeB((size_t)N_EDGES * L);
    __hip_bfloat16* ln16  = takeB((size_t)N_EDGES * L);
    __hip_bfloat16* agg16 = takeB((size_t)N_NODES * L);
    __hip_bfloat16* fN16  = takeB((size_t)N_NODES * 32);
    __hip_bfloat16* fE16  = takeB((size_t)N_EDGES * 32);
    int* deg    = takeI(N_NODES);
    int* rowptr = takeI(N_NODES + 1);
    int* cursor = takeI(N_NODES);
    int* elist  = takeI(N_EDGES);
    int* ssnd   = takeI(N_EDGES);
    int* srcv   = takeI(N_EDGES);

    const dim3 blk(NTHR);
    const dim3 grdE((N_EDGES + 63) / 64);     // 1250
    const dim3 grdN((N_NODES + 63) / 64);     // 157

    (void)hipMemsetAsync(cnt, 0, sizeof(int), stream);
    (void)hipMemsetAsync(deg, 0, N_NODES * sizeof(int), stream);
    detect_dtype<<<dim3(64), blk, 0, stream>>>((const uint32_t*)d_in[0], cnt);
    transpose_all<<<dim3(512), blk, 0, stream>>>(ta, cnt, wpool);

    csr_hist<<<dim3(80), blk, 0, stream>>>(rcv, deg);
    csr_scan<<<dim3(1), blk, 0, stream>>>(deg, rowptr, cursor);
    csr_scatter<<<dim3(80), blk, 0, stream>>>(rcv, cursor, elist);
    sort_meta<<<dim3(80), blk, 0, stream>>>(snd, rcv, elist, ssnd, srcv);
    convert_feats<<<dim3(256), blk, 0, stream>>>(d_in[0], d_in[1], cnt, elist, fN16, fE16);

    // ---- encoders (edge streams in sorted order) ----
    fused_mlp<A_PLAIN, E_LN_STORE, 3, 32><<<grdE, blk, 0, stream>>>(
        fE16, 32, N_EDGES, wmat[3], wmat[4], wmat[5],
        d_in[13], d_in[15], d_in[17], d_in[18], d_in[19], 0, cnt,
        nullptr, nullptr, nullptr, nullptr, nullptr,
        e32, e16, nullptr, nullptr, nullptr, nullptr);
    fused_mlp<A_PLAIN, E_LN_STORE, 3, 32><<<grdN, blk, 0, stream>>>(
        fN16, 32, N_NODES, wmat[0], wmat[1], wmat[2],
        d_in[5], d_in[7], d_in[9], d_in[10], d_in[11], 0, cnt,
        nullptr, nullptr, nullptr, nullptr, nullptr,
        n32, n16, nullptr, nullptr, nullptr, nullptr);

    // ---- processor ----
    for (int s = 0; s < STEPS; s++) {
        const int po = s * L;
        fused_mlp<A_FEAT, E_LN_EDGE, 3, 384><<<grdE, blk, 0, stream>>>(
            nullptr, 0, N_EDGES,
            wmat[6] + (size_t)s * 128 * 384,
            wmat[7] + (size_t)s * 128 * 128,
            wmat[8] + (size_t)s * 128 * 128,
            d_in[21], d_in[23], d_in[25], d_in[26], d_in[27], po, cnt,
            n16, e16, nullptr, ssnd, srcv,
            e32, e16, ln16, nullptr, nullptr, nullptr);
        csr_agg<<<dim3((N_NODES + 7) / 8), blk, 0, stream>>>(rowptr, ln16, agg16);
        fused_mlp<A_CAT, E_LN_NODE, 3, 256><<<grdN, blk, 0, stream>>>(
            nullptr, 0, N_NODES,
            wmat[9]  + (size_t)s * 128 * 256,
            wmat[10] + (size_t)s * 128 * 128,
            wmat[11] + (size_t)s * 128 * 128,
            d_in[29], d_in[31], d_in[33], d_in[34], d_in[35], po, cnt,
            n16, nullptr, agg16, nullptr, nullptr,
            n32, n16, nullptr, nullptr, nullptr, nullptr);
    }

    // ---- decoder ----
    fused_mlp<A_PLAIN, E_DEC, 2, 128><<<grdN, blk, 0, stream>>>(
        n16, 128, N_NODES, wmat[12], wmat[13], nullptr,
        d_in[37], d_in[39], nullptr, nullptr, nullptr, 0, cnt,
        nullptr, nullptr, nullptr, nullptr, nullptr,
        nullptr, nullptr, nullptr, d_in[40], d_in[41], d_out);
}

// Round 10
// 1319.969 us; speedup vs baseline: 1.1089x; 1.1089x over previous
//
#include <hip/hip_runtime.h>
#include <hip/hip_bf16.h>
#include <stdint.h>

// ---------------------------------------------------------------------------
// EncodeProcessDecode (MeshGraphNets) on MI355X — Round 10:
//  r7 base (best measured: 1328 us) with exactly two deltas:
//   * __launch_bounds__ min-waves 3 -> 4 (LDS 27.6 KB permits 5 blocks/CU)
//   * XCD-chunking block swizzle (bid%8)*per + bid/8 so receiver-adjacent
//     blocks (which share gathered n16 rows) land on the same XCD L2
//  Numerics bit-identical (absmax 0.0703125).
//
#define N_NODES 10000
#define N_EDGES 80000
#define L 128
#define STEPS 15
#define LN_EPS 1e-5f
#define NTHR 256
#define H_STRIDE 272

typedef short short8 __attribute__((ext_vector_type(8)));
typedef float floatx4 __attribute__((ext_vector_type(4)));

__device__ __forceinline__ float bf2f(const __hip_bfloat16 x) {
    return __bfloat162float(x);
}
__device__ __forceinline__ float ldmix(const void* p, int idx, int isf32) {
    return isf32 ? ((const float*)p)[idx]
                 : bf2f(((const __hip_bfloat16*)p)[idx]);
}

// ---------------------------------------------------------------------------
__global__ void detect_dtype(const uint32_t* __restrict__ nf, int* cnt) {
    int c = 0;
    for (int i = blockIdx.x * blockDim.x + threadIdx.x; i < 60000;
         i += gridDim.x * blockDim.x) {
        const uint32_t w = nf[i];
        c += (((w >> 7) & 0xFF) >= 0xC6) + (((w >> 23) & 0xFF) >= 0xC6);
    }
    atomicAdd(cnt, c);
}

// ---------------------------------------------------------------------------
#define N_TMATS 14
struct TAll {
    const void* src[N_TMATS];
    long long cum[N_TMATS + 1];
    int K[N_TMATS], N[N_TMATS], Kpad[N_TMATS];
};

__global__ void transpose_all(TAll a, const int* __restrict__ cnt,
                              __hip_bfloat16* __restrict__ pool) {
    const int isf32 = (*cnt > 1000);
    const long long total = a.cum[N_TMATS];
    for (long long i = blockIdx.x * (long long)blockDim.x + threadIdx.x;
         i < total; i += gridDim.x * (long long)blockDim.x) {
        int e = 0;
        #pragma unroll 1
        for (int j = 1; j < N_TMATS; j++) if (i >= a.cum[j]) e = j;
        const long long r = i - a.cum[e];
        const int per = a.N[e] * a.Kpad[e];
        const int m = (int)(r / per);
        const int r2 = (int)(r - (long long)m * per);
        const int nn = r2 / a.Kpad[e];
        const int kk = r2 - nn * a.Kpad[e];
        float v = 0.f;
        if (kk < a.K[e]) v = ldmix(a.src[e], (m * a.K[e] + kk) * a.N[e] + nn, isf32);
        pool[i] = __float2bfloat16(v);
    }
}

// fN plain; fE permuted to sorted-edge order via elist
__global__ void convert_feats(const void* __restrict__ nf,
                              const void* __restrict__ ef,
                              const int* __restrict__ cnt,
                              const int* __restrict__ elist,
                              __hip_bfloat16* __restrict__ fN,
                              __hip_bfloat16* __restrict__ fE)
{
    const int isf32 = (*cnt > 1000);
    const int totN = N_NODES * 32;
    const int totE = N_EDGES * 32;
    for (int i = blockIdx.x * blockDim.x + threadIdx.x; i < totN + totE;
         i += gridDim.x * blockDim.x) {
        if (i < totN) {
            const int r = i >> 5, c = i & 31;
            fN[i] = __float2bfloat16(c < 12 ? ldmix(nf, r * 12 + c, isf32) : 0.f);
        } else {
            const int j = i - totN;
            const int r = j >> 5, c = j & 31;
            const int e = elist[r];
            fE[j] = __float2bfloat16(c < 7 ? ldmix(ef, e * 7 + c, isf32) : 0.f);
        }
    }
}

// ---------------------------------------------------------------------------
// CSR build (receiver lists)
__global__ void csr_hist(const int* __restrict__ rcv, int* __restrict__ deg) {
    for (int i = blockIdx.x * blockDim.x + threadIdx.x; i < N_EDGES;
         i += gridDim.x * blockDim.x)
        atomicAdd(&deg[rcv[i]], 1);
}

__global__ void csr_scan(const int* __restrict__ deg, int* __restrict__ rowptr,
                         int* __restrict__ cursor) {
    __shared__ int part[256];
    __shared__ int partx[257];
    const int t = threadIdx.x;
    int s = 0;
    for (int j = 0; j < 40; j++) {
        const int i = t * 40 + j;
        if (i < N_NODES) s += deg[i];
    }
    part[t] = s;
    __syncthreads();
    if (t == 0) {
        int r = 0;
        for (int k = 0; k < 256; k++) { partx[k] = r; r += part[k]; }
        partx[256] = r;
    }
    __syncthreads();
    int run = partx[t];
    for (int j = 0; j < 40; j++) {
        const int i = t * 40 + j;
        if (i < N_NODES) {
            rowptr[i] = run;
            cursor[i] = run;
            run += deg[i];
        }
    }
    if (t == 255) rowptr[N_NODES] = partx[256];
}

__global__ void csr_scatter(const int* __restrict__ rcv, int* __restrict__ cursor,
                            int* __restrict__ elist) {
    for (int i = blockIdx.x * blockDim.x + threadIdx.x; i < N_EDGES;
         i += gridDim.x * blockDim.x) {
        const int p = atomicAdd(&cursor[rcv[i]], 1);
        elist[p] = i;
    }
}

__global__ void sort_meta(const int* __restrict__ snd, const int* __restrict__ rcv,
                          const int* __restrict__ elist,
                          int* __restrict__ ssnd, int* __restrict__ srcv) {
    for (int i = blockIdx.x * blockDim.x + threadIdx.x; i < N_EDGES;
         i += gridDim.x * blockDim.x) {
        const int e = elist[i];
        ssnd[i] = snd[e];
        srcv[i] = rcv[e];
    }
}

// agg16[v] = bf16( sum over contiguous sorted rows [rowptr[v],rowptr[v+1]) )
__global__ __launch_bounds__(256)
void csr_agg(const int* __restrict__ rowptr,
             const __hip_bfloat16* __restrict__ ln16,
             __hip_bfloat16* __restrict__ agg16)
{
    const int g = threadIdx.x >> 5;
    const int lane = threadIdx.x & 31;
    const int v = blockIdx.x * 8 + g;
    if (v >= N_NODES) return;
    const int c0 = lane * 4;
    float s0 = 0.f, s1 = 0.f, s2 = 0.f, s3 = 0.f;
    int j = rowptr[v];
    const int en = rowptr[v + 1];
    for (; j + 1 < en; j += 2) {
        union { uint2 w; __hip_bfloat16 h[4]; } u0, u1;
        u0.w = *(const uint2*)(ln16 + (size_t)j * L + c0);
        u1.w = *(const uint2*)(ln16 + (size_t)(j + 1) * L + c0);
        s0 += bf2f(u0.h[0]); s1 += bf2f(u0.h[1]); s2 += bf2f(u0.h[2]); s3 += bf2f(u0.h[3]);
        s0 += bf2f(u1.h[0]); s1 += bf2f(u1.h[1]); s2 += bf2f(u1.h[2]); s3 += bf2f(u1.h[3]);
    }
    for (; j < en; j++) {
        union { uint2 w; __hip_bfloat16 h[4]; } u;
        u.w = *(const uint2*)(ln16 + (size_t)j * L + c0);
        s0 += bf2f(u.h[0]); s1 += bf2f(u.h[1]); s2 += bf2f(u.h[2]); s3 += bf2f(u.h[3]);
    }
    union { uint2 w; __hip_bfloat16 h[4]; } o;
    o.h[0] = __float2bfloat16(s0); o.h[1] = __float2bfloat16(s1);
    o.h[2] = __float2bfloat16(s2); o.h[3] = __float2bfloat16(s3);
    *(uint2*)(agg16 + (size_t)v * L + c0) = o.w;
}

// ---------------------------------------------------------------------------
enum AMode { A_PLAIN = 0, A_FEAT = 1, A_CAT = 2 };
enum Epi   { E_LN_STORE = 0, E_LN_EDGE = 1, E_LN_NODE = 2, E_DEC = 3 };

// Fused NL-layer MLP. Block: 64 rows x 128 cols, 4 waves. r7 structure.
template <int AMODE, int EPI, int NL>
__global__ __launch_bounds__(NTHR, 4)
void fused_mlp(const __hip_bfloat16* __restrict__ A, int lda, int M, int K0,
               const __hip_bfloat16* __restrict__ WT0,
               const __hip_bfloat16* __restrict__ WT1,
               const __hip_bfloat16* __restrict__ WT2,
               const void* __restrict__ b0,
               const void* __restrict__ b1,
               const void* __restrict__ b2,
               const void* __restrict__ g,
               const void* __restrict__ beta,
               int poff,
               const int* __restrict__ cnt,
               const __hip_bfloat16* __restrict__ n16,
               const __hip_bfloat16* __restrict__ e16s,
               const __hip_bfloat16* __restrict__ agg16,
               const int* __restrict__ ssnd,
               const int* __restrict__ srcv,
               float* res32,
               __hip_bfloat16* res16,
               __hip_bfloat16* __restrict__ lnout,
               const void* __restrict__ dW,
               const void* __restrict__ db,
               void* __restrict__ dout)
{
    __shared__ __align__(16) char lds[17408 + 10240];
    char* AsB = lds;                // 64 rows * 80 B staging (overlaps h region? no: separate)
    char* WsB = lds + 17408;

    // XCD-chunking swizzle: consecutive work chunks stay on one XCD.
    const int nb  = gridDim.x;
    const int per = nb >> 3;
    const int bid = blockIdx.x;
    int sb = bid;
    if (bid < per * 8) sb = (bid & 7) * per + (bid >> 3);

    const int tid  = threadIdx.x;
    const int wv   = tid >> 6;
    const int lane = tid & 63;
    const int quad = lane >> 4;
    const int m15  = lane & 15;
    const int row0 = sb * 64;
    const int isf32 = (*cnt > 1000);

    char* hw = lds + wv * 4352;     // wave's 16x128 activation buffer

    const int boff = m15 * 80 + quad * 16;
    const int aoff = (wv * 16 + m15) * 80 + quad * 16;

    const int aq   = tid & 3;
    const int arow = tid >> 2;      // 0..63
    int sidx = 0, ridx = 0;
    {
        const int rg = row0 + arow;
        if constexpr (AMODE == A_FEAT) {
            sidx = (rg < M) ? ssnd[rg] : 0;
            ridx = (rg < M) ? srcv[rg] : 0;
        }
    }

    auto loadA = [&](int k0) -> int4 {
        const int rg = row0 + arow;
        int4 av = make_int4(0, 0, 0, 0);
        if (rg < M) {
            if constexpr (AMODE == A_PLAIN) {
                av = *(const int4*)(A + (size_t)rg * lda + k0 + aq * 8);
            } else if constexpr (AMODE == A_FEAT) {
                const __hip_bfloat16* sp;
                if (k0 < 2 * L) {
                    const int nd = (k0 < L) ? sidx : ridx;
                    sp = n16 + (size_t)nd * L + (k0 & (L - 1)) + aq * 8;
                } else {
                    sp = e16s + (size_t)rg * L + (k0 - 2 * L) + aq * 8;
                }
                av = *(const int4*)sp;
            } else { // A_CAT
                const __hip_bfloat16* sp = (k0 < L)
                    ? n16   + (size_t)rg * L + k0 + aq * 8
                    : agg16 + (size_t)rg * L + (k0 - L) + aq * 8;
                av = *(const int4*)sp;
            }
        }
        return av;
    };
    auto loadW = [&](const __hip_bfloat16* WT, int ksz, int k0) -> int4 {
        return *(const int4*)(WT + (size_t)(tid >> 2) * ksz + k0 + aq * 8);
    };
    // W staging covers rows 0..63 with 256 threads (tid>>2), second half via +64
    auto loadW2 = [&](const __hip_bfloat16* WT, int ksz, int k0) -> int4 {
        return *(const int4*)(WT + (size_t)((tid >> 2) + 64) * ksz + k0 + aq * 8);
    };

    floatx4 acc[8];

    // ===================== layer 0 (reg-prefetch) =====================
    #pragma unroll
    for (int ct = 0; ct < 8; ct++) acc[ct] = (floatx4)0.f;

    int4 pA = loadA(0);
    int4 pW0 = loadW(WT0, K0, 0);
    int4 pW1 = loadW2(WT0, K0, 0);

    for (int k0 = 0; k0 < K0; k0 += 32) {
        *(int4*)(AsB + arow * 80 + aq * 16) = pA;
        *(int4*)(WsB + arow * 80 + aq * 16)        = pW0;
        *(int4*)(WsB + (arow + 64) * 80 + aq * 16) = pW1;
        __syncthreads();
        if (k0 + 32 < K0) {
            pA  = loadA(k0 + 32);
            pW0 = loadW(WT0, K0, k0 + 32);
            pW1 = loadW2(WT0, K0, k0 + 32);
        }
        const short8 a = *(const short8*)(AsB + aoff);
        #pragma unroll
        for (int ct = 0; ct < 8; ct++) {
            const short8 b = *(const short8*)(WsB + boff + ct * 1280);
            acc[ct] = __builtin_amdgcn_mfma_f32_16x16x32_bf16(a, b, acc[ct], 0, 0, 0);
        }
        __syncthreads();
    }
    {
        float bb[8];
        #pragma unroll
        for (int ct = 0; ct < 8; ct++) bb[ct] = ldmix(b0, poff + ct * 16 + m15, isf32);
        #pragma unroll
        for (int ct = 0; ct < 8; ct++)
            #pragma unroll
            for (int i = 0; i < 4; i++) {
                const int rl = quad * 4 + i;
                const int col = ct * 16 + m15;
                *(__hip_bfloat16*)(hw + rl * H_STRIDE + col * 2) =
                    __float2bfloat16(fmaxf(acc[ct][i] + bb[ct], 0.f));
            }
    }

    // ===================== layer 1 =====================
    {
        #pragma unroll
        for (int ct = 0; ct < 8; ct++) acc[ct] = (floatx4)0.f;
        short8 af[4];
        #pragma unroll
        for (int c = 0; c < 4; c++)
            af[c] = *(const short8*)(hw + m15 * H_STRIDE + c * 64 + quad * 16);
        int4 qW0 = loadW(WT1, L, 0);
        int4 qW1 = loadW2(WT1, L, 0);
        for (int c = 0; c < 4; c++) {
            *(int4*)(WsB + arow * 80 + aq * 16)        = qW0;
            *(int4*)(WsB + (arow + 64) * 80 + aq * 16) = qW1;
            __syncthreads();
            if (c < 3) {
                qW0 = loadW(WT1, L, (c + 1) * 32);
                qW1 = loadW2(WT1, L, (c + 1) * 32);
            }
            #pragma unroll
            for (int ct = 0; ct < 8; ct++) {
                const short8 b = *(const short8*)(WsB + boff + ct * 1280);
                acc[ct] = __builtin_amdgcn_mfma_f32_16x16x32_bf16(af[c], b, acc[ct], 0, 0, 0);
            }
            __syncthreads();
        }
        float bb[8];
        #pragma unroll
        for (int ct = 0; ct < 8; ct++) bb[ct] = ldmix(b1, poff + ct * 16 + m15, isf32);
        #pragma unroll
        for (int ct = 0; ct < 8; ct++)
            #pragma unroll
            for (int i = 0; i < 4; i++) {
                const int rl = quad * 4 + i;
                const int col = ct * 16 + m15;
                *(__hip_bfloat16*)(hw + rl * H_STRIDE + col * 2) =
                    __float2bfloat16(fmaxf(acc[ct][i] + bb[ct], 0.f));
            }
    }

    if constexpr (NL == 3) {
        // ===================== layer 2 + LN epilogue =====================
        #pragma unroll
        for (int ct = 0; ct < 8; ct++) acc[ct] = (floatx4)0.f;
        short8 af[4];
        #pragma unroll
        for (int c = 0; c < 4; c++)
            af[c] = *(const short8*)(hw + m15 * H_STRIDE + c * 64 + quad * 16);
        int4 qW0 = loadW(WT2, L, 0);
        int4 qW1 = loadW2(WT2, L, 0);
        for (int c = 0; c < 4; c++) {
            *(int4*)(WsB + arow * 80 + aq * 16)        = qW0;
            *(int4*)(WsB + (arow + 64) * 80 + aq * 16) = qW1;
            __syncthreads();
            if (c < 3) {
                qW0 = loadW(WT2, L, (c + 1) * 32);
                qW1 = loadW2(WT2, L, (c + 1) * 32);
            }
            #pragma unroll
            for (int ct = 0; ct < 8; ct++) {
                const short8 b = *(const short8*)(WsB + boff + ct * 1280);
                acc[ct] = __builtin_amdgcn_mfma_f32_16x16x32_bf16(af[c], b, acc[ct], 0, 0, 0);
            }
            __syncthreads();
        }
        float bb[8], gg[8], be[8];
        #pragma unroll
        for (int ct = 0; ct < 8; ct++) {
            bb[ct] = ldmix(b2,   poff + ct * 16 + m15, isf32);
            gg[ct] = ldmix(g,    poff + ct * 16 + m15, isf32);
            be[ct] = ldmix(beta, poff + ct * 16 + m15, isf32);
        }
        #pragma unroll
        for (int i = 0; i < 4; i++) {
            float t[8], s = 0.f, s2 = 0.f;
            #pragma unroll
            for (int ct = 0; ct < 8; ct++) {
                t[ct] = acc[ct][i] + bb[ct];
                s  += t[ct];
                s2 += t[ct] * t[ct];
            }
            #pragma unroll
            for (int m = 1; m < 16; m <<= 1) {
                s  += __shfl_xor(s,  m, 64);
                s2 += __shfl_xor(s2, m, 64);
            }
            const float mean = s * (1.f / 128.f);
            const float var  = s2 * (1.f / 128.f) - mean * mean;
            const float inv  = rsqrtf(fmaxf(var, 0.f) + LN_EPS);
            const int rg = row0 + wv * 16 + quad * 4 + i;
            if (rg < M) {
                #pragma unroll
                for (int ct = 0; ct < 8; ct++) {
                    const int col = ct * 16 + m15;
                    const float o = (t[ct] - mean) * inv * gg[ct] + be[ct];
                    const size_t idx = (size_t)rg * L + col;
                    if constexpr (EPI == E_LN_STORE) {
                        res32[idx] = o;
                        if (res16) res16[idx] = __float2bfloat16(o);
                    } else if constexpr (EPI == E_LN_NODE) {
                        const float nw = res32[idx] + o;
                        res32[idx] = nw;
                        res16[idx] = __float2bfloat16(nw);
                    } else { // E_LN_EDGE
                        const float nw = res32[idx] + o;
                        res32[idx] = nw;
                        res16[idx] = __float2bfloat16(nw);
                        lnout[idx] = __float2bfloat16(o);
                    }
                }
            }
        }
    } else {
        // ===================== decoder head =====================
        __syncthreads();
        float* Wl = (float*)WsB;
        for (int i = tid; i < 3 * L; i += NTHR) {
            const int o = i / L, k = i - o * L;
            Wl[o * L + k] = ldmix(dW, k * 3 + o, isf32);
        }
        __syncthreads();
        if (tid < 64) {
            const int rg = row0 + tid;
            if (rg < M) {
                const __hip_bfloat16* hr =
                    (const __hip_bfloat16*)(lds + (tid >> 4) * 4352 + (tid & 15) * H_STRIDE);
                float s0 = ldmix(db, 0, isf32);
                float s1 = ldmix(db, 1, isf32);
                float s2 = ldmix(db, 2, isf32);
                #pragma unroll 8
                for (int k = 0; k < L; k++) {
                    const float hv = bf2f(hr[k]);
                    s0 += hv * Wl[k];
                    s1 += hv * Wl[L + k];
                    s2 += hv * Wl[2 * L + k];
                }
                if (isf32) {
                    float* o = (float*)dout;
                    o[rg * 3 + 0] = s0; o[rg * 3 + 1] = s1; o[rg * 3 + 2] = s2;
                } else {
                    __hip_bfloat16* o = (__hip_bfloat16*)dout;
                    o[rg * 3 + 0] = __float2bfloat16(s0);
                    o[rg * 3 + 1] = __float2bfloat16(s1);
                    o[rg * 3 + 2] = __float2bfloat16(s2);
                }
            }
        }
    }
}

// ---------------------------------------------------------------------------
extern "C" void kernel_launch(void* const* d_in, const int* in_sizes, int n_in,
                              void* d_out, int out_size, void* d_ws, size_t ws_size,
                              hipStream_t stream)
{
    (void)in_sizes; (void)n_in; (void)out_size; (void)ws_size;
    const int* snd = (const int*)d_in[2];
    const int* rcv = (const int*)d_in[3];

    char* ws = (char*)d_ws;
    int* cnt = (int*)ws;                              ws += 256;
    auto takeB = [&](size_t el) {
        __hip_bfloat16* p = (__hip_bfloat16*)ws;
        ws += ((el * 2 + 255) & ~255ull);
        return p;
    };
    auto takeF = [&](size_t el) {
        float* p = (float*)ws;
        ws += ((el * 4 + 255) & ~255ull);
        return p;
    };
    auto takeI = [&](size_t el) {
        int* p = (int*)ws;
        ws += ((el * 4 + 255) & ~255ull);
        return p;
    };

    const int srcIdx[N_TMATS] = {4, 6, 8, 12, 14, 16, 20, 22, 24, 28, 30, 32, 36, 38};
    const int tK[N_TMATS]    = {12, 128, 128, 7, 128, 128, 384, 128, 128, 256, 128, 128, 128, 128};
    const int tKp[N_TMATS]   = {32, 128, 128, 32, 128, 128, 384, 128, 128, 256, 128, 128, 128, 128};
    const int tNm[N_TMATS]   = {1, 1, 1, 1, 1, 1, STEPS, STEPS, STEPS, STEPS, STEPS, STEPS, 1, 1};
    TAll ta;
    long long cum = 0;
    __hip_bfloat16* wmat[N_TMATS];
    __hip_bfloat16* wpool = (__hip_bfloat16*)ws;
    for (int j = 0; j < N_TMATS; j++) {
        ta.src[j] = d_in[srcIdx[j]];
        ta.cum[j] = cum;
        ta.K[j] = tK[j]; ta.N[j] = 128; ta.Kpad[j] = tKp[j];
        wmat[j] = wpool + cum;
        cum += (long long)tNm[j] * 128 * tKp[j];
    }
    ta.cum[N_TMATS] = cum;
    ws += ((cum * 2 + 255) & ~255ull);

    float* n32 = takeF((size_t)N_NODES * L);
    float* e32 = takeF((size_t)N_EDGES * L);
    __hip_bfloat16* n16   = takeB((size_t)N_NODES * L);
    __hip_bfloat16* e16   = takeB((size_t)N_EDGES * L);
    __hip_bfloat16* ln16  = takeB((size_t)N_EDGES * L);
    __hip_bfloat16* agg16 = takeB((size_t)N_NODES * L);
    __hip_bfloat16* fN16  = takeB((size_t)N_NODES * 32);
    __hip_bfloat16* fE16  = takeB((size_t)N_EDGES * 32);
    int* deg    = takeI(N_NODES);
    int* rowptr = takeI(N_NODES + 1);
    int* cursor = takeI(N_NODES);
    int* elist  = takeI(N_EDGES);
    int* ssnd   = takeI(N_EDGES);
    int* srcv   = takeI(N_EDGES);

    const dim3 blk(NTHR);
    const dim3 grdE((N_EDGES + 63) / 64);     // 1250
    const dim3 grdN((N_NODES + 63) / 64);     // 157

    (void)hipMemsetAsync(cnt, 0, sizeof(int), stream);
    (void)hipMemsetAsync(deg, 0, N_NODES * sizeof(int), stream);
    detect_dtype<<<dim3(64), blk, 0, stream>>>((const uint32_t*)d_in[0], cnt);
    transpose_all<<<dim3(512), blk, 0, stream>>>(ta, cnt, wpool);

    csr_hist<<<dim3(80), blk, 0, stream>>>(rcv, deg);
    csr_scan<<<dim3(1), blk, 0, stream>>>(deg, rowptr, cursor);
    csr_scatter<<<dim3(80), blk, 0, stream>>>(rcv, cursor, elist);
    sort_meta<<<dim3(80), blk, 0, stream>>>(snd, rcv, elist, ssnd, srcv);
    convert_feats<<<dim3(256), blk, 0, stream>>>(d_in[0], d_in[1], cnt, elist, fN16, fE16);

    // ---- encoders (edge streams in sorted order) ----
    fused_mlp<A_PLAIN, E_LN_STORE, 3><<<grdE, blk, 0, stream>>>(
        fE16, 32, N_EDGES, 32, wmat[3], wmat[4], wmat[5],
        d_in[13], d_in[15], d_in[17], d_in[18], d_in[19], 0, cnt,
        nullptr, nullptr, nullptr, nullptr, nullptr,
        e32, e16, nullptr, nullptr, nullptr, nullptr);
    fused_mlp<A_PLAIN, E_LN_STORE, 3><<<grdN, blk, 0, stream>>>(
        fN16, 32, N_NODES, 32, wmat[0], wmat[1], wmat[2],
        d_in[5], d_in[7], d_in[9], d_in[10], d_in[11], 0, cnt,
        nullptr, nullptr, nullptr, nullptr, nullptr,
        n32, n16, nullptr, nullptr, nullptr, nullptr);

    // ---- processor ----
    for (int s = 0; s < STEPS; s++) {
        const int po = s * L;
        fused_mlp<A_FEAT, E_LN_EDGE, 3><<<grdE, blk, 0, stream>>>(
            nullptr, 0, N_EDGES, 384,
            wmat[6] + (size_t)s * 128 * 384,
            wmat[7] + (size_t)s * 128 * 128,
            wmat[8] + (size_t)s * 128 * 128,
            d_in[21], d_in[23], d_in[25], d_in[26], d_in[27], po, cnt,
            n16, e16, nullptr, ssnd, srcv,
            e32, e16, ln16, nullptr, nullptr, nullptr);
        csr_agg<<<dim3((N_NODES + 7) / 8), blk, 0, stream>>>(rowptr, ln16, agg16);
        fused_mlp<A_CAT, E_LN_NODE, 3><<<grdN, blk, 0, stream>>>(
            nullptr, 0, N_NODES, 256,
            wmat[9]  + (size_t)s * 128 * 256,
            wmat[10] + (size_t)s * 128 * 128,
            wmat[11] + (size_t)s * 128 * 128,
            d_in[29], d_in[31], d_in[33], d_in[34], d_in[35], po, cnt,
            n16, nullptr, agg16, nullptr, nullptr,
            n32, n16, nullptr, nullptr, nullptr, nullptr);
    }

    // ---- decoder ----
    fused_mlp<A_PLAIN, E_DEC, 2><<<grdN, blk, 0, stream>>>(
        n16, 128, N_NODES, 128, wmat[12], wmat[13], nullptr,
        d_in[37], d_in[39], nullptr, nullptr, nullptr, 0, cnt,
        nullptr, nullptr, nullptr, nullptr, nullptr,
        nullptr, nullptr, nullptr, d_in[40], d_in[41], d_out);
}

// Round 11
// 1201.654 us; speedup vs baseline: 1.2181x; 1.0985x over previous
//
#include <hip/hip_runtime.h>
#include <hip/hip_bf16.h>
#include <stdint.h>

// ---------------------------------------------------------------------------
// EncodeProcessDecode (MeshGraphNets) on MI355X — Round 11:
//  r10 base with ONE change: LN epilogue stores vectorized via f32 LDS
//  round-trip (two 32-row passes). Per-thread epilogue vmem instructions drop
//  from ~128 scalar to ~24 vectorized; numerics bit-identical (o staged in
//  f32, same accumulation order / rounding points; absmax 0.0703125).
//
#define N_NODES 10000
#define N_EDGES 80000
#define L 128
#define STEPS 15
#define LN_EPS 1e-5f
#define NTHR 256
#define H_STRIDE 272

typedef short short8 __attribute__((ext_vector_type(8)));
typedef float floatx4 __attribute__((ext_vector_type(4)));

__device__ __forceinline__ float bf2f(const __hip_bfloat16 x) {
    return __bfloat162float(x);
}
__device__ __forceinline__ float ldmix(const void* p, int idx, int isf32) {
    return isf32 ? ((const float*)p)[idx]
                 : bf2f(((const __hip_bfloat16*)p)[idx]);
}

// ---------------------------------------------------------------------------
__global__ void detect_dtype(const uint32_t* __restrict__ nf, int* cnt) {
    int c = 0;
    for (int i = blockIdx.x * blockDim.x + threadIdx.x; i < 60000;
         i += gridDim.x * blockDim.x) {
        const uint32_t w = nf[i];
        c += (((w >> 7) & 0xFF) >= 0xC6) + (((w >> 23) & 0xFF) >= 0xC6);
    }
    atomicAdd(cnt, c);
}

// ---------------------------------------------------------------------------
#define N_TMATS 14
struct TAll {
    const void* src[N_TMATS];
    long long cum[N_TMATS + 1];
    int K[N_TMATS], N[N_TMATS], Kpad[N_TMATS];
};

__global__ void transpose_all(TAll a, const int* __restrict__ cnt,
                              __hip_bfloat16* __restrict__ pool) {
    const int isf32 = (*cnt > 1000);
    const long long total = a.cum[N_TMATS];
    for (long long i = blockIdx.x * (long long)blockDim.x + threadIdx.x;
         i < total; i += gridDim.x * (long long)blockDim.x) {
        int e = 0;
        #pragma unroll 1
        for (int j = 1; j < N_TMATS; j++) if (i >= a.cum[j]) e = j;
        const long long r = i - a.cum[e];
        const int per = a.N[e] * a.Kpad[e];
        const int m = (int)(r / per);
        const int r2 = (int)(r - (long long)m * per);
        const int nn = r2 / a.Kpad[e];
        const int kk = r2 - nn * a.Kpad[e];
        float v = 0.f;
        if (kk < a.K[e]) v = ldmix(a.src[e], (m * a.K[e] + kk) * a.N[e] + nn, isf32);
        pool[i] = __float2bfloat16(v);
    }
}

// fN plain; fE permuted to sorted-edge order via elist
__global__ void convert_feats(const void* __restrict__ nf,
                              const void* __restrict__ ef,
                              const int* __restrict__ cnt,
                              const int* __restrict__ elist,
                              __hip_bfloat16* __restrict__ fN,
                              __hip_bfloat16* __restrict__ fE)
{
    const int isf32 = (*cnt > 1000);
    const int totN = N_NODES * 32;
    const int totE = N_EDGES * 32;
    for (int i = blockIdx.x * blockDim.x + threadIdx.x; i < totN + totE;
         i += gridDim.x * blockDim.x) {
        if (i < totN) {
            const int r = i >> 5, c = i & 31;
            fN[i] = __float2bfloat16(c < 12 ? ldmix(nf, r * 12 + c, isf32) : 0.f);
        } else {
            const int j = i - totN;
            const int r = j >> 5, c = j & 31;
            const int e = elist[r];
            fE[j] = __float2bfloat16(c < 7 ? ldmix(ef, e * 7 + c, isf32) : 0.f);
        }
    }
}

// ---------------------------------------------------------------------------
// CSR build (receiver lists)
__global__ void csr_hist(const int* __restrict__ rcv, int* __restrict__ deg) {
    for (int i = blockIdx.x * blockDim.x + threadIdx.x; i < N_EDGES;
         i += gridDim.x * blockDim.x)
        atomicAdd(&deg[rcv[i]], 1);
}

__global__ void csr_scan(const int* __restrict__ deg, int* __restrict__ rowptr,
                         int* __restrict__ cursor) {
    __shared__ int part[256];
    __shared__ int partx[257];
    const int t = threadIdx.x;
    int s = 0;
    for (int j = 0; j < 40; j++) {
        const int i = t * 40 + j;
        if (i < N_NODES) s += deg[i];
    }
    part[t] = s;
    __syncthreads();
    if (t == 0) {
        int r = 0;
        for (int k = 0; k < 256; k++) { partx[k] = r; r += part[k]; }
        partx[256] = r;
    }
    __syncthreads();
    int run = partx[t];
    for (int j = 0; j < 40; j++) {
        const int i = t * 40 + j;
        if (i < N_NODES) {
            rowptr[i] = run;
            cursor[i] = run;
            run += deg[i];
        }
    }
    if (t == 255) rowptr[N_NODES] = partx[256];
}

__global__ void csr_scatter(const int* __restrict__ rcv, int* __restrict__ cursor,
                            int* __restrict__ elist) {
    for (int i = blockIdx.x * blockDim.x + threadIdx.x; i < N_EDGES;
         i += gridDim.x * blockDim.x) {
        const int p = atomicAdd(&cursor[rcv[i]], 1);
        elist[p] = i;
    }
}

__global__ void sort_meta(const int* __restrict__ snd, const int* __restrict__ rcv,
                          const int* __restrict__ elist,
                          int* __restrict__ ssnd, int* __restrict__ srcv) {
    for (int i = blockIdx.x * blockDim.x + threadIdx.x; i < N_EDGES;
         i += gridDim.x * blockDim.x) {
        const int e = elist[i];
        ssnd[i] = snd[e];
        srcv[i] = rcv[e];
    }
}

// agg16[v] = bf16( sum over contiguous sorted rows [rowptr[v],rowptr[v+1]) )
__global__ __launch_bounds__(256)
void csr_agg(const int* __restrict__ rowptr,
             const __hip_bfloat16* __restrict__ ln16,
             __hip_bfloat16* __restrict__ agg16)
{
    const int g = threadIdx.x >> 5;
    const int lane = threadIdx.x & 31;
    const int v = blockIdx.x * 8 + g;
    if (v >= N_NODES) return;
    const int c0 = lane * 4;
    float s0 = 0.f, s1 = 0.f, s2 = 0.f, s3 = 0.f;
    int j = rowptr[v];
    const int en = rowptr[v + 1];
    for (; j + 1 < en; j += 2) {
        union { uint2 w; __hip_bfloat16 h[4]; } u0, u1;
        u0.w = *(const uint2*)(ln16 + (size_t)j * L + c0);
        u1.w = *(const uint2*)(ln16 + (size_t)(j + 1) * L + c0);
        s0 += bf2f(u0.h[0]); s1 += bf2f(u0.h[1]); s2 += bf2f(u0.h[2]); s3 += bf2f(u0.h[3]);
        s0 += bf2f(u1.h[0]); s1 += bf2f(u1.h[1]); s2 += bf2f(u1.h[2]); s3 += bf2f(u1.h[3]);
    }
    for (; j < en; j++) {
        union { uint2 w; __hip_bfloat16 h[4]; } u;
        u.w = *(const uint2*)(ln16 + (size_t)j * L + c0);
        s0 += bf2f(u.h[0]); s1 += bf2f(u.h[1]); s2 += bf2f(u.h[2]); s3 += bf2f(u.h[3]);
    }
    union { uint2 w; __hip_bfloat16 h[4]; } o;
    o.h[0] = __float2bfloat16(s0); o.h[1] = __float2bfloat16(s1);
    o.h[2] = __float2bfloat16(s2); o.h[3] = __float2bfloat16(s3);
    *(uint2*)(agg16 + (size_t)v * L + c0) = o.w;
}

// ---------------------------------------------------------------------------
enum AMode { A_PLAIN = 0, A_FEAT = 1, A_CAT = 2 };
enum Epi   { E_LN_STORE = 0, E_LN_EDGE = 1, E_LN_NODE = 2, E_DEC = 3 };

// Fused NL-layer MLP. Block: 64 rows x 128 cols, 4 waves. r7/r10 structure
// with vectorized LN epilogue (f32 LDS stage, 2x32-row flush passes).
template <int AMODE, int EPI, int NL>
__global__ __launch_bounds__(NTHR, 4)
void fused_mlp(const __hip_bfloat16* __restrict__ A, int lda, int M, int K0,
               const __hip_bfloat16* __restrict__ WT0,
               const __hip_bfloat16* __restrict__ WT1,
               const __hip_bfloat16* __restrict__ WT2,
               const void* __restrict__ b0,
               const void* __restrict__ b1,
               const void* __restrict__ b2,
               const void* __restrict__ g,
               const void* __restrict__ beta,
               int poff,
               const int* __restrict__ cnt,
               const __hip_bfloat16* __restrict__ n16,
               const __hip_bfloat16* __restrict__ e16s,
               const __hip_bfloat16* __restrict__ agg16,
               const int* __restrict__ ssnd,
               const int* __restrict__ srcv,
               float* res32,
               __hip_bfloat16* res16,
               __hip_bfloat16* __restrict__ lnout,
               const void* __restrict__ dW,
               const void* __restrict__ db,
               void* __restrict__ dout)
{
    __shared__ __align__(16) char lds[17408 + 10240];
    char* AsB = lds;
    char* WsB = lds + 17408;

    // XCD-chunking swizzle (neutral but kept from r10)
    const int nb  = gridDim.x;
    const int per = nb >> 3;
    const int bid = blockIdx.x;
    int sb = bid;
    if (bid < per * 8) sb = (bid & 7) * per + (bid >> 3);

    const int tid  = threadIdx.x;
    const int wv   = tid >> 6;
    const int lane = tid & 63;
    const int quad = lane >> 4;
    const int m15  = lane & 15;
    const int row0 = sb * 64;
    const int isf32 = (*cnt > 1000);

    char* hw = lds + wv * 4352;     // wave's 16x128 activation buffer

    const int boff = m15 * 80 + quad * 16;
    const int aoff = (wv * 16 + m15) * 80 + quad * 16;

    const int aq   = tid & 3;
    const int arow = tid >> 2;      // 0..63
    int sidx = 0, ridx = 0;
    {
        const int rg = row0 + arow;
        if constexpr (AMODE == A_FEAT) {
            sidx = (rg < M) ? ssnd[rg] : 0;
            ridx = (rg < M) ? srcv[rg] : 0;
        }
    }

    auto loadA = [&](int k0) -> int4 {
        const int rg = row0 + arow;
        int4 av = make_int4(0, 0, 0, 0);
        if (rg < M) {
            if constexpr (AMODE == A_PLAIN) {
                av = *(const int4*)(A + (size_t)rg * lda + k0 + aq * 8);
            } else if constexpr (AMODE == A_FEAT) {
                const __hip_bfloat16* sp;
                if (k0 < 2 * L) {
                    const int nd = (k0 < L) ? sidx : ridx;
                    sp = n16 + (size_t)nd * L + (k0 & (L - 1)) + aq * 8;
                } else {
                    sp = e16s + (size_t)rg * L + (k0 - 2 * L) + aq * 8;
                }
                av = *(const int4*)sp;
            } else { // A_CAT
                const __hip_bfloat16* sp = (k0 < L)
                    ? n16   + (size_t)rg * L + k0 + aq * 8
                    : agg16 + (size_t)rg * L + (k0 - L) + aq * 8;
                av = *(const int4*)sp;
            }
        }
        return av;
    };
    auto loadW = [&](const __hip_bfloat16* WT, int ksz, int k0) -> int4 {
        return *(const int4*)(WT + (size_t)(tid >> 2) * ksz + k0 + aq * 8);
    };
    auto loadW2 = [&](const __hip_bfloat16* WT, int ksz, int k0) -> int4 {
        return *(const int4*)(WT + (size_t)((tid >> 2) + 64) * ksz + k0 + aq * 8);
    };

    floatx4 acc[8];

    // ===================== layer 0 (reg-prefetch) =====================
    #pragma unroll
    for (int ct = 0; ct < 8; ct++) acc[ct] = (floatx4)0.f;

    int4 pA = loadA(0);
    int4 pW0 = loadW(WT0, K0, 0);
    int4 pW1 = loadW2(WT0, K0, 0);

    for (int k0 = 0; k0 < K0; k0 += 32) {
        *(int4*)(AsB + arow * 80 + aq * 16) = pA;
        *(int4*)(WsB + arow * 80 + aq * 16)        = pW0;
        *(int4*)(WsB + (arow + 64) * 80 + aq * 16) = pW1;
        __syncthreads();
        if (k0 + 32 < K0) {
            pA  = loadA(k0 + 32);
            pW0 = loadW(WT0, K0, k0 + 32);
            pW1 = loadW2(WT0, K0, k0 + 32);
        }
        const short8 a = *(const short8*)(AsB + aoff);
        #pragma unroll
        for (int ct = 0; ct < 8; ct++) {
            const short8 b = *(const short8*)(WsB + boff + ct * 1280);
            acc[ct] = __builtin_amdgcn_mfma_f32_16x16x32_bf16(a, b, acc[ct], 0, 0, 0);
        }
        __syncthreads();
    }
    {
        float bb[8];
        #pragma unroll
        for (int ct = 0; ct < 8; ct++) bb[ct] = ldmix(b0, poff + ct * 16 + m15, isf32);
        #pragma unroll
        for (int ct = 0; ct < 8; ct++)
            #pragma unroll
            for (int i = 0; i < 4; i++) {
                const int rl = quad * 4 + i;
                const int col = ct * 16 + m15;
                *(__hip_bfloat16*)(hw + rl * H_STRIDE + col * 2) =
                    __float2bfloat16(fmaxf(acc[ct][i] + bb[ct], 0.f));
            }
    }

    // ===================== layer 1 =====================
    {
        #pragma unroll
        for (int ct = 0; ct < 8; ct++) acc[ct] = (floatx4)0.f;
        short8 af[4];
        #pragma unroll
        for (int c = 0; c < 4; c++)
            af[c] = *(const short8*)(hw + m15 * H_STRIDE + c * 64 + quad * 16);
        int4 qW0 = loadW(WT1, L, 0);
        int4 qW1 = loadW2(WT1, L, 0);
        for (int c = 0; c < 4; c++) {
            *(int4*)(WsB + arow * 80 + aq * 16)        = qW0;
            *(int4*)(WsB + (arow + 64) * 80 + aq * 16) = qW1;
            __syncthreads();
            if (c < 3) {
                qW0 = loadW(WT1, L, (c + 1) * 32);
                qW1 = loadW2(WT1, L, (c + 1) * 32);
            }
            #pragma unroll
            for (int ct = 0; ct < 8; ct++) {
                const short8 b = *(const short8*)(WsB + boff + ct * 1280);
                acc[ct] = __builtin_amdgcn_mfma_f32_16x16x32_bf16(af[c], b, acc[ct], 0, 0, 0);
            }
            __syncthreads();
        }
        float bb[8];
        #pragma unroll
        for (int ct = 0; ct < 8; ct++) bb[ct] = ldmix(b1, poff + ct * 16 + m15, isf32);
        #pragma unroll
        for (int ct = 0; ct < 8; ct++)
            #pragma unroll
            for (int i = 0; i < 4; i++) {
                const int rl = quad * 4 + i;
                const int col = ct * 16 + m15;
                *(__hip_bfloat16*)(hw + rl * H_STRIDE + col * 2) =
                    __float2bfloat16(fmaxf(acc[ct][i] + bb[ct], 0.f));
            }
    }

    if constexpr (NL == 3) {
        // ===================== layer 2 + LN epilogue =====================
        #pragma unroll
        for (int ct = 0; ct < 8; ct++) acc[ct] = (floatx4)0.f;
        short8 af[4];
        #pragma unroll
        for (int c = 0; c < 4; c++)
            af[c] = *(const short8*)(hw + m15 * H_STRIDE + c * 64 + quad * 16);
        int4 qW0 = loadW(WT2, L, 0);
        int4 qW1 = loadW2(WT2, L, 0);
        for (int c = 0; c < 4; c++) {
            *(int4*)(WsB + arow * 80 + aq * 16)        = qW0;
            *(int4*)(WsB + (arow + 64) * 80 + aq * 16) = qW1;
            __syncthreads();
            if (c < 3) {
                qW0 = loadW(WT2, L, (c + 1) * 32);
                qW1 = loadW2(WT2, L, (c + 1) * 32);
            }
            #pragma unroll
            for (int ct = 0; ct < 8; ct++) {
                const short8 b = *(const short8*)(WsB + boff + ct * 1280);
                acc[ct] = __builtin_amdgcn_mfma_f32_16x16x32_bf16(af[c], b, acc[ct], 0, 0, 0);
            }
            __syncthreads();
        }
        float bb[8], gg[8], be[8];
        #pragma unroll
        for (int ct = 0; ct < 8; ct++) {
            bb[ct] = ldmix(b2,   poff + ct * 16 + m15, isf32);
            gg[ct] = ldmix(g,    poff + ct * 16 + m15, isf32);
            be[ct] = ldmix(beta, poff + ct * 16 + m15, isf32);
        }
        // compute LN outputs into registers (same math/order as before)
        float ov[4][8];
        #pragma unroll
        for (int i = 0; i < 4; i++) {
            float t[8], s = 0.f, s2 = 0.f;
            #pragma unroll
            for (int ct = 0; ct < 8; ct++) {
                t[ct] = acc[ct][i] + bb[ct];
                s  += t[ct];
                s2 += t[ct] * t[ct];
            }
            #pragma unroll
            for (int m = 1; m < 16; m <<= 1) {
                s  += __shfl_xor(s,  m, 64);
                s2 += __shfl_xor(s2, m, 64);
            }
            const float mean = s * (1.f / 128.f);
            const float var  = s2 * (1.f / 128.f) - mean * mean;
            const float inv  = rsqrtf(fmaxf(var, 0.f) + LN_EPS);
            #pragma unroll
            for (int ct = 0; ct < 8; ct++)
                ov[i][ct] = (t[ct] - mean) * inv * gg[ct] + be[ct];
        }
        // stage o (f32) in LDS, flush vectorized in two 32-row passes.
        // stg row stride = 132 floats (528 B) to break 4-quad bank aliasing.
        float* stg = (float*)lds;     // all of LDS is dead now
        const int mypass = wv >> 1;
        const int rloc   = (wv & 1) * 16 + quad * 4;   // + i, 0..31
        #pragma unroll
        for (int p = 0; p < 2; p++) {
            if (mypass == p) {
                #pragma unroll
                for (int i = 0; i < 4; i++)
                    #pragma unroll
                    for (int ct = 0; ct < 8; ct++)
                        stg[(rloc + i) * 132 + ct * 16 + m15] = ov[i][ct];
            }
            __syncthreads();
            #pragma unroll
            for (int it = 0; it < 4; it++) {
                const int flat = it * NTHR + tid;       // 0..1023
                const int r  = flat >> 5;               // 0..31
                const int c4 = (flat & 31) * 4;
                const int rg = row0 + p * 32 + r;
                if (rg < M) {
                    const float4 o4 = *(const float4*)&stg[r * 132 + c4];
                    const size_t idx = (size_t)rg * L + c4;
                    union { uint2 w; __hip_bfloat16 h[4]; } pk;
                    if constexpr (EPI == E_LN_STORE) {
                        *(float4*)&res32[idx] = o4;
                        pk.h[0] = __float2bfloat16(o4.x); pk.h[1] = __float2bfloat16(o4.y);
                        pk.h[2] = __float2bfloat16(o4.z); pk.h[3] = __float2bfloat16(o4.w);
                        *(uint2*)(res16 + idx) = pk.w;
                    } else {
                        float4 nw = *(const float4*)&res32[idx];
                        nw.x += o4.x; nw.y += o4.y; nw.z += o4.z; nw.w += o4.w;
                        *(float4*)&res32[idx] = nw;
                        pk.h[0] = __float2bfloat16(nw.x); pk.h[1] = __float2bfloat16(nw.y);
                        pk.h[2] = __float2bfloat16(nw.z); pk.h[3] = __float2bfloat16(nw.w);
                        *(uint2*)(res16 + idx) = pk.w;
                        if constexpr (EPI == E_LN_EDGE) {
                            pk.h[0] = __float2bfloat16(o4.x); pk.h[1] = __float2bfloat16(o4.y);
                            pk.h[2] = __float2bfloat16(o4.z); pk.h[3] = __float2bfloat16(o4.w);
                            *(uint2*)(lnout + idx) = pk.w;
                        }
                    }
                }
            }
            __syncthreads();
        }
    } else {
        // ===================== decoder head =====================
        __syncthreads();
        float* Wl = (float*)WsB;
        for (int i = tid; i < 3 * L; i += NTHR) {
            const int o = i / L, k = i - o * L;
            Wl[o * L + k] = ldmix(dW, k * 3 + o, isf32);
        }
        __syncthreads();
        if (tid < 64) {
            const int rg = row0 + tid;
            if (rg < M) {
                const __hip_bfloat16* hr =
                    (const __hip_bfloat16*)(lds + (tid >> 4) * 4352 + (tid & 15) * H_STRIDE);
                float s0 = ldmix(db, 0, isf32);
                float s1 = ldmix(db, 1, isf32);
                float s2 = ldmix(db, 2, isf32);
                #pragma unroll 8
                for (int k = 0; k < L; k++) {
                    const float hv = bf2f(hr[k]);
                    s0 += hv * Wl[k];
                    s1 += hv * Wl[L + k];
                    s2 += hv * Wl[2 * L + k];
                }
                if (isf32) {
                    float* o = (float*)dout;
                    o[rg * 3 + 0] = s0; o[rg * 3 + 1] = s1; o[rg * 3 + 2] = s2;
                } else {
                    __hip_bfloat16* o = (__hip_bfloat16*)dout;
                    o[rg * 3 + 0] = __float2bfloat16(s0);
                    o[rg * 3 + 1] = __float2bfloat16(s1);
                    o[rg * 3 + 2] = __float2bfloat16(s2);
                }
            }
        }
    }
}

// ---------------------------------------------------------------------------
extern "C" void kernel_launch(void* const* d_in, const int* in_sizes, int n_in,
                              void* d_out, int out_size, void* d_ws, size_t ws_size,
                              hipStream_t stream)
{
    (void)in_sizes; (void)n_in; (void)out_size; (void)ws_size;
    const int* snd = (const int*)d_in[2];
    const int* rcv = (const int*)d_in[3];

    char* ws = (char*)d_ws;
    int* cnt = (int*)ws;                              ws += 256;
    auto takeB = [&](size_t el) {
        __hip_bfloat16* p = (__hip_bfloat16*)ws;
        ws += ((el * 2 + 255) & ~255ull);
        return p;
    };
    auto takeF = [&](size_t el) {
        float* p = (float*)ws;
        ws += ((el * 4 + 255) & ~255ull);
        return p;
    };
    auto takeI = [&](size_t el) {
        int* p = (int*)ws;
        ws += ((el * 4 + 255) & ~255ull);
        return p;
    };

    const int srcIdx[N_TMATS] = {4, 6, 8, 12, 14, 16, 20, 22, 24, 28, 30, 32, 36, 38};
    const int tK[N_TMATS]    = {12, 128, 128, 7, 128, 128, 384, 128, 128, 256, 128, 128, 128, 128};
    const int tKp[N_TMATS]   = {32, 128, 128, 32, 128, 128, 384, 128, 128, 256, 128, 128, 128, 128};
    const int tNm[N_TMATS]   = {1, 1, 1, 1, 1, 1, STEPS, STEPS, STEPS, STEPS, STEPS, STEPS, 1, 1};
    TAll ta;
    long long cum = 0;
    __hip_bfloat16* wmat[N_TMATS];
    __hip_bfloat16* wpool = (__hip_bfloat16*)ws;
    for (int j = 0; j < N_TMATS; j++) {
        ta.src[j] = d_in[srcIdx[j]];
        ta.cum[j] = cum;
        ta.K[j] = tK[j]; ta.N[j] = 128; ta.Kpad[j] = tKp[j];
        wmat[j] = wpool + cum;
        cum += (long long)tNm[j] * 128 * tKp[j];
    }
    ta.cum[N_TMATS] = cum;
    ws += ((cum * 2 + 255) & ~255ull);

    float* n32 = takeF((size_t)N_NODES * L);
    float* e32 = takeF((size_t)N_EDGES * L);
    __hip_bfloat16* n16   = takeB((size_t)N_NODES * L);
    __hip_bfloat16* e16   = takeB((size_t)N_EDGES * L);
    __hip_bfloat16* ln16  = takeB((size_t)N_EDGES * L);
    __hip_bfloat16* agg16 = takeB((size_t)N_NODES * L);
    __hip_bfloat16* fN16  = takeB((size_t)N_NODES * 32);
    __hip_bfloat16* fE16  = takeB((size_t)N_EDGES * 32);
    int* deg    = takeI(N_NODES);
    int* rowptr = takeI(N_NODES + 1);
    int* cursor = takeI(N_NODES);
    int* elist  = takeI(N_EDGES);
    int* ssnd   = takeI(N_EDGES);
    int* srcv   = takeI(N_EDGES);

    const dim3 blk(NTHR);
    const dim3 grdE((N_EDGES + 63) / 64);     // 1250
    const dim3 grdN((N_NODES + 63) / 64);     // 157

    (void)hipMemsetAsync(cnt, 0, sizeof(int), stream);
    (void)hipMemsetAsync(deg, 0, N_NODES * sizeof(int), stream);
    detect_dtype<<<dim3(64), blk, 0, stream>>>((const uint32_t*)d_in[0], cnt);
    transpose_all<<<dim3(512), blk, 0, stream>>>(ta, cnt, wpool);

    csr_hist<<<dim3(80), blk, 0, stream>>>(rcv, deg);
    csr_scan<<<dim3(1), blk, 0, stream>>>(deg, rowptr, cursor);
    csr_scatter<<<dim3(80), blk, 0, stream>>>(rcv, cursor, elist);
    sort_meta<<<dim3(80), blk, 0, stream>>>(snd, rcv, elist, ssnd, srcv);
    convert_feats<<<dim3(256), blk, 0, stream>>>(d_in[0], d_in[1], cnt, elist, fN16, fE16);

    // ---- encoders (edge streams in sorted order) ----
    fused_mlp<A_PLAIN, E_LN_STORE, 3><<<grdE, blk, 0, stream>>>(
        fE16, 32, N_EDGES, 32, wmat[3], wmat[4], wmat[5],
        d_in[13], d_in[15], d_in[17], d_in[18], d_in[19], 0, cnt,
        nullptr, nullptr, nullptr, nullptr, nullptr,
        e32, e16, nullptr, nullptr, nullptr, nullptr);
    fused_mlp<A_PLAIN, E_LN_STORE, 3><<<grdN, blk, 0, stream>>>(
        fN16, 32, N_NODES, 32, wmat[0], wmat[1], wmat[2],
        d_in[5], d_in[7], d_in[9], d_in[10], d_in[11], 0, cnt,
        nullptr, nullptr, nullptr, nullptr, nullptr,
        n32, n16, nullptr, nullptr, nullptr, nullptr);

    // ---- processor ----
    for (int s = 0; s < STEPS; s++) {
        const int po = s * L;
        fused_mlp<A_FEAT, E_LN_EDGE, 3><<<grdE, blk, 0, stream>>>(
            nullptr, 0, N_EDGES, 384,
            wmat[6] + (size_t)s * 128 * 384,
            wmat[7] + (size_t)s * 128 * 128,
            wmat[8] + (size_t)s * 128 * 128,
            d_in[21], d_in[23], d_in[25], d_in[26], d_in[27], po, cnt,
            n16, e16, nullptr, ssnd, srcv,
            e32, e16, ln16, nullptr, nullptr, nullptr);
        csr_agg<<<dim3((N_NODES + 7) / 8), blk, 0, stream>>>(rowptr, ln16, agg16);
        fused_mlp<A_CAT, E_LN_NODE, 3><<<grdN, blk, 0, stream>>>(
            nullptr, 0, N_NODES, 256,
            wmat[9]  + (size_t)s * 128 * 256,
            wmat[10] + (size_t)s * 128 * 128,
            wmat[11] + (size_t)s * 128 * 128,
            d_in[29], d_in[31], d_in[33], d_in[34], d_in[35], po, cnt,
            n16, nullptr, agg16, nullptr, nullptr,
            n32, n16, nullptr, nullptr, nullptr, nullptr);
    }

    // ---- decoder ----
    fused_mlp<A_PLAIN, E_DEC, 2><<<grdN, blk, 0, stream>>>(
        n16, 128, N_NODES, 128, wmat[12], wmat[13], nullptr,
        d_in[37], d_in[39], nullptr, nullptr, nullptr, 0, cnt,
        nullptr, nullptr, nullptr, nullptr, nullptr,
        nullptr, nullptr, nullptr, d_in[40], d_in[41], d_out);
}